// Round 15
// baseline (469.553 us; speedup 1.0000x reference)
//
#include <hip/hip_runtime.h>
#include <hip/hip_fp16.h>
#include <math.h>

// simple_GAT: 5-layer GAT (heads=1) + BN(eval) + mean-pool + linear.
// R15: (1) GEMM fp8 output via LDS bounce -> coalesced uint4 stores (was 32
// scattered byte-stores/wave); (2) k_bscan folded into k_bfinal (each block
// sums bcnt prefix itself); (3) aggr gather unroll 16. Keep k_mega, k_prep,
// slab CSR, 2-nodes/wave fp8 aggr (its 90MB FETCH = verified compulsory
// per-XCD floor).

#define NN 100000
#define NE 1600000
#define DH 128
#define NL 5
#define NG 64

static constexpr int ET = NE + NN;            // edges + self loops
static constexpr int NBK = (NN + 255) >> 8;   // 391 buckets of 256 dst nodes
static constexpr int CAP = 6144;              // slab capacity (mean 4348, sd 66)
static constexpr int GB0 = (NN + 127) / 128;  // 782 gemm blocks
static constexpr int SBK = (ET + 4095) / 4096;// 416 scatter blocks in k_mega
static constexpr int PW = (NL * DH * DH) / 256;        // 320
static constexpr int PB = (NL * DH + 255) / 256;       // 3
static constexpr int PC = (NN + 4095) / 4096;          // 25
static constexpr int LROW = 144;              // bounce-tile row stride (bytes)

typedef __attribute__((ext_vector_type(8))) _Float16 f16x8;
typedef __attribute__((ext_vector_type(4))) float f32x4;
typedef __attribute__((ext_vector_type(2))) float f32x2;

__device__ __forceinline__ unsigned short f2h(float v) {
    __half h = __float2half(v);
    return *reinterpret_cast<unsigned short*>(&h);
}
__device__ __forceinline__ float h2f(unsigned short u) {
    __half h = *reinterpret_cast<__half*>(&u);
    return __half2float(h);
}

// ---- fused prep: W transpose-cast | BN fold | graph counts ----------------

__global__ __launch_bounds__(256) void k_prep(const float* __restrict__ W,
                                              unsigned short* __restrict__ wtg,
                                              const float* __restrict__ ga,
                                              const float* __restrict__ be,
                                              const float* __restrict__ me,
                                              const float* __restrict__ va,
                                              float* __restrict__ g2,
                                              float* __restrict__ b2,
                                              const int* __restrict__ batch,
                                              int* __restrict__ cnts) {
    __shared__ int hc[NG];
    int bid = blockIdx.x, t = threadIdx.x;
    if (bid < PW) {
        int i = bid * 256 + t;
        int l = i >> 14, rem = i & 16383;
        int k = rem >> 7, c = rem & 127;
        wtg[(l << 14) + (c << 7) + k] = f2h(W[i]);   // wtg[l][c][k] = W[l][k][c]
    } else if (bid < PW + PB) {
        int i = (bid - PW) * 256 + t;
        if (i < NL * DH) {
            float s = ga[i] * rsqrtf(va[i] + 1e-5f);
            g2[i] = s;
            b2[i] = be[i] - me[i] * s;
        }
    } else {
        if (t < NG) hc[t] = 0;
        __syncthreads();
        int base = (bid - PW - PB) * 4096;
#pragma unroll
        for (int k = 0; k < 16; ++k) {
            int i = base + k * 256 + t;
            if (i < NN) atomicAdd(&hc[batch[i]], 1);
        }
        __syncthreads();
        if (t < NG && hc[t]) atomicAdd(&cnts[t], hc[t]);
    }
}

// ---- GEMM body (device): xp = h @ W + fused dots + fp8 out (LDS bounce) ---

template <bool F32IN>
__device__ __forceinline__ void gemm_body(char* lds, int bid,
                                          const void* __restrict__ Av,
                                          const unsigned short* __restrict__ Wt,
                                          const float* __restrict__ a_s,
                                          const float* __restrict__ a_d,
                                          unsigned char* __restrict__ xq,
                                          float* __restrict__ s_node,
                                          float* __restrict__ d_node) {
    int tid = threadIdx.x;
    int w = tid >> 6, l = tid & 63;
    int row0 = bid * 128;
    {   // stage Wt[col][k] fp16 with swizzle; 512 threads x 64B each
        int col = tid >> 2, seg = tid & 3;
        const char* srcp = (const char*)Wt + col * 256 + seg * 64;
#pragma unroll
        for (int i = 0; i < 4; ++i) {
            int off = seg * 64 + i * 16;
            *(uint4*)(lds + col * 256 + (off ^ ((col & 7) << 4))) =
                *(const uint4*)(srcp + i * 16);
        }
    }
    int arow = row0 + w * 16 + (l & 15);
    int arc = min(arow, NN - 1);
    f16x8 af[4];
    if constexpr (F32IN) {
        const float* ap = (const float*)Av + (size_t)arc * DH + ((l >> 4) << 3);
#pragma unroll
        for (int ks = 0; ks < 4; ++ks) {
            float4 u0 = *(const float4*)(ap + ks * 32);
            float4 u1 = *(const float4*)(ap + ks * 32 + 4);
            f16x8 v = {(_Float16)u0.x, (_Float16)u0.y, (_Float16)u0.z, (_Float16)u0.w,
                       (_Float16)u1.x, (_Float16)u1.y, (_Float16)u1.z, (_Float16)u1.w};
            af[ks] = v;
        }
    } else {
        const unsigned short* ap =
            (const unsigned short*)Av + (size_t)arc * DH + ((l >> 4) << 3);
#pragma unroll
        for (int ks = 0; ks < 4; ++ks)
            af[ks] = *(const f16x8*)(ap + ks * 32);
    }
    __syncthreads();

    f32x4 acc[8];
#pragma unroll
    for (int ct = 0; ct < 8; ++ct) acc[ct] = (f32x4){0.f, 0.f, 0.f, 0.f};
#pragma unroll
    for (int ct = 0; ct < 8; ++ct) {
        int col = ct * 16 + (l & 15);
        int cb = col * 256;
        int sw = (col & 7) << 4;
#pragma unroll
        for (int ks = 0; ks < 4; ++ks) {
            f16x8 bfr = *(const f16x8*)(lds + cb + ((ks * 64 + ((l >> 4) << 4)) ^ sw));
            acc[ct] = __builtin_amdgcn_mfma_f32_16x16x32_f16(af[ks], bfr, acc[ct], 0, 0, 0);
        }
    }

    float asv[8], adv[8];
#pragma unroll
    for (int ct = 0; ct < 8; ++ct) {
        asv[ct] = a_s[ct * 16 + (l & 15)];
        adv[ct] = a_d[ct * 16 + (l & 15)];
    }
    float ps[4] = {0.f, 0.f, 0.f, 0.f}, pd[4] = {0.f, 0.f, 0.f, 0.f};
#pragma unroll
    for (int ct = 0; ct < 8; ++ct)
#pragma unroll
        for (int r = 0; r < 4; ++r) {
            ps[r] = fmaf(acc[ct][r], asv[ct], ps[r]);
            pd[r] = fmaf(acc[ct][r], adv[ct], pd[r]);
        }
#pragma unroll
    for (int off = 8; off >= 1; off >>= 1)
#pragma unroll
        for (int r = 0; r < 4; ++r) {
            ps[r] += __shfl_xor(ps[r], off, 64);
            pd[r] += __shfl_xor(pd[r], off, 64);
        }
    int rbase = row0 + w * 16 + ((l >> 4) << 2);
    if ((l & 15) == 0) {
#pragma unroll
        for (int r = 0; r < 4; ++r) {
            int row = rbase + r;
            if (row < NN) { s_node[row] = ps[r]; d_node[row] = pd[r]; }
        }
    }

    // fp8 output via LDS bounce: byte-writes into stride-144 tile, then
    // coalesced uint4 stores (block tile = rows row0..row0+127 contiguous).
    __syncthreads();                 // W region reuse: all MFMA reads done
    int rl0 = w * 16 + ((l >> 4) << 2);
#pragma unroll
    for (int r = 0; r < 4; ++r) {
#pragma unroll
        for (int ct = 0; ct < 8; ++ct) {
            int pk = __builtin_amdgcn_cvt_pk_fp8_f32(acc[ct][r], 0.f, 0, false);
            lds[(rl0 + r) * LROW + ct * 16 + (l & 15)] = (char)(pk & 0xff);
        }
    }
    __syncthreads();
    size_t base = (size_t)row0 * DH;
    size_t limit = (size_t)NN * DH;
#pragma unroll
    for (int p = 0; p < 2; ++p) {
        int q = (tid + p * 512) * 16;             // byte pos in 16KB tile
        if (base + q < limit) {
            int row = q >> 7, col = q & 127;
            *(uint4*)(xq + base + q) = *(const uint4*)(lds + row * LROW + col);
        }
    }
}

// ---- CSR slab-scatter body (device) ---------------------------------------

__device__ __forceinline__ void bscatter_body(char* smem, int bid,
                                              const int* __restrict__ src,
                                              const int* __restrict__ dst,
                                              int* __restrict__ bcnt,
                                              int* __restrict__ pairs) {
    int* lcnt = (int*)smem;
    int* lbase = lcnt + NBK;
    for (int i = threadIdx.x; i < NBK; i += 512) lcnt[i] = 0;
    __syncthreads();
    int base = bid * 4096;
    int es[8], ed[8], er[8];
#pragma unroll
    for (int k = 0; k < 8; ++k) {
        int i = base + k * 512 + threadIdx.x;
        if (i < ET) {
            int s, d;
            if (i < NE) { s = src[i]; d = dst[i]; } else { s = d = i - NE; }
            es[k] = s; ed[k] = d;
            er[k] = atomicAdd(&lcnt[d >> 8], 1);
        } else {
            ed[k] = -1;
        }
    }
    __syncthreads();
    for (int i = threadIdx.x; i < NBK; i += 512)
        lbase[i] = lcnt[i] ? atomicAdd(&bcnt[i], lcnt[i]) : 0;
    __syncthreads();
#pragma unroll
    for (int k = 0; k < 8; ++k) {
        if (ed[k] >= 0) {
            int bk = ed[k] >> 8;
            pairs[(size_t)bk * CAP + lbase[bk] + er[k]] =
                es[k] | ((ed[k] & 255) << 17);
        }
    }
}

// ---- k_mega: layer-0 GEMM || CSR scatter (independent, one dispatch) ------

__global__ __launch_bounds__(512) void k_mega(const float* __restrict__ x,
                                              const unsigned short* __restrict__ Wt,
                                              const float* __restrict__ a_s,
                                              const float* __restrict__ a_d,
                                              unsigned char* __restrict__ xq,
                                              float* __restrict__ s_node,
                                              float* __restrict__ d_node,
                                              const int* __restrict__ src,
                                              const int* __restrict__ dst,
                                              int* __restrict__ bcnt,
                                              int* __restrict__ pairs) {
    __shared__ __align__(16) char smem[32768];
    if (blockIdx.x < GB0)
        gemm_body<true>(smem, blockIdx.x, x, Wt, a_s, a_d, xq, s_node, d_node);
    else
        bscatter_body(smem, blockIdx.x - GB0, src, dst, bcnt, pairs);
}

// ---- standalone GEMM for layers 1-4 ---------------------------------------

__global__ __launch_bounds__(512) void k_gemm(const unsigned short* __restrict__ A,
                                              const unsigned short* __restrict__ Wt,
                                              const float* __restrict__ a_s,
                                              const float* __restrict__ a_d,
                                              unsigned char* __restrict__ xq,
                                              float* __restrict__ s_node,
                                              float* __restrict__ d_node) {
    __shared__ __align__(16) char lds[32768];
    gemm_body<false>(lds, blockIdx.x, A, Wt, a_s, a_d, xq, s_node, d_node);
}

// ---- CSR finalize (self-computed prefix; k_bscan eliminated) --------------

__global__ __launch_bounds__(256) void k_bfinal(const int* __restrict__ pairs,
                                                const int* __restrict__ bcnt,
                                                int* __restrict__ row_ptr,
                                                int* __restrict__ csr_src) {
    __shared__ int ldeg[256];
    __shared__ int lcur[256];
    __shared__ int sm[256];
    int b = blockIdx.x, t = threadIdx.x;
    int n0 = b << 8;
    // compute e0 = sum(bcnt[0..b)) in-block (bcnt is 1.5KB, L2-hot)
    int psum = 0;
    for (int j = t; j < b; j += 256) psum += bcnt[j];
    sm[t] = psum;
    __syncthreads();
    for (int off = 128; off >= 1; off >>= 1) {
        if (t < off) sm[t] += sm[t + off];
        __syncthreads();
    }
    int e0 = sm[0];
    int cb = bcnt[b];
    __syncthreads();
    const int* slab = pairs + (size_t)b * CAP;
    ldeg[t] = 0;
    __syncthreads();
    for (int j = t; j < cb; j += 256)
        atomicAdd(&ldeg[(slab[j] >> 17) & 255], 1);
    __syncthreads();
    int v = ldeg[t];
    sm[t] = v;
    __syncthreads();
    for (int off = 1; off < 256; off <<= 1) {
        int u = (t >= off) ? sm[t - off] : 0;
        __syncthreads();
        sm[t] += u;
        __syncthreads();
    }
    int excl = sm[t] - v;
    lcur[t] = excl;
    int n = n0 + t;
    if (n < NN) row_ptr[n] = e0 + excl;
    if (b == 0 && t == 0) row_ptr[NN] = ET;
    __syncthreads();
    for (int j = t; j < cb; j += 256) {
        int p = slab[j];
        int local = atomicAdd(&lcur[(p >> 17) & 255], 1);
        csr_src[e0 + local] = p & 0x1FFFF;
    }
}

// ---- aggregation: 2 nodes per wave (half-wave per node); fp8 gather -------

__global__ __launch_bounds__(256) void k_aggr(const unsigned char* __restrict__ xq,
                                              const float* __restrict__ s_node,
                                              const float* __restrict__ d_node,
                                              const int* __restrict__ row_ptr,
                                              const int* __restrict__ csr_src,
                                              const float* __restrict__ bias,
                                              const float* __restrict__ g2,
                                              const float* __restrict__ b2,
                                              unsigned short* __restrict__ hout) {
    __shared__ float2 stash[4][2][64];
    int wid = threadIdx.x >> 6, lane = threadIdx.x & 63;
    int hi = lane >> 5, cl = lane & 31;
    int n = blockIdx.x * 8 + wid * 2 + hi;   // NN % 8 == 0 -> always valid
    int s0 = row_ptr[n], s1 = row_ptr[n + 1];
    int deg = s1 - s0;
    float dn = d_node[n];

    // prologue: slots cl and cl+32 of this node's edge list (deg<=64 typical)
    int off0 = 0, off1 = 0;
    float e0 = -1e30f, e1 = -1e30f;
    {
        int j0 = s0 + cl;
        if (j0 < s1) {
            int s = csr_src[j0];
            off0 = s << 7;                       // byte offset of fp8 row
            float t = s_node[s] + dn;
            e0 = (t >= 0.f) ? t : 0.2f * t;
        }
        int j1 = s0 + 32 + cl;
        if (j1 < s1) {
            int s = csr_src[j1];
            off1 = s << 7;
            float t = s_node[s] + dn;
            e1 = (t >= 0.f) ? t : 0.2f * t;
        }
    }
    float mx = fmaxf(e0, e1);
    for (int j = s0 + 64 + cl; j < s1; j += 32) {      // never in practice
        int s = csr_src[j];
        float t = s_node[s] + dn;
        t = (t >= 0.f) ? t : 0.2f * t;
        mx = fmaxf(mx, t);
    }
#pragma unroll
    for (int off = 16; off >= 1; off >>= 1)
        mx = fmaxf(mx, __shfl_xor(mx, off, 32));       // width-32: per-half

    float w0 = (e0 > -1e29f) ? __expf(e0 - mx) : 0.f;
    float w1 = (e1 > -1e29f) ? __expf(e1 - mx) : 0.f;
    float denom = w0 + w1;
#pragma unroll
    for (int off = 16; off >= 1; off >>= 1)
        denom += __shfl_xor(denom, off, 32);

    stash[wid][hi][cl]      = make_float2(w0, __int_as_float(off0));
    stash[wid][hi][cl + 32] = make_float2(w1, __int_as_float(off1));

    // gather: half-wave per edge; 4B fp8 per lane; HW pk decode; unroll 16
    unsigned int cl4 = (unsigned int)cl << 2;
    const char* xbase = (const char*)xq;
    float acc0 = 0.f, acc1 = 0.f, acc2 = 0.f, acc3 = 0.f;
    int cnt = min(deg, 64);
#pragma unroll 16
    for (int t = 0; t < cnt; ++t) {
        float2 p = stash[wid][hi][t];
        float w = p.x;
        unsigned int voff = (unsigned int)__float_as_int(p.y) + cl4;
        unsigned int v = *(const unsigned int*)(xbase + voff);
        f32x2 d0 = __builtin_amdgcn_cvt_pk_f32_fp8(v, false);
        f32x2 d1 = __builtin_amdgcn_cvt_pk_f32_fp8(v, true);
        acc0 = fmaf(w, d0[0], acc0);
        acc1 = fmaf(w, d0[1], acc1);
        acc2 = fmaf(w, d1[0], acc2);
        acc3 = fmaf(w, d1[1], acc3);
    }
    // tail fallback for deg>64 (statistically never; kept for correctness)
    for (int j = s0 + 64; j < s1; ++j) {
        int s = csr_src[j];
        float t = s_node[s] + dn;
        t = (t >= 0.f) ? t : 0.2f * t;
        float w = __expf(t - mx);
        denom += w;
        unsigned int voff = ((unsigned int)s << 7) + cl4;
        unsigned int v = *(const unsigned int*)(xbase + voff);
        f32x2 d0 = __builtin_amdgcn_cvt_pk_f32_fp8(v, false);
        f32x2 d1 = __builtin_amdgcn_cvt_pk_f32_fp8(v, true);
        acc0 = fmaf(w, d0[0], acc0);
        acc1 = fmaf(w, d0[1], acc1);
        acc2 = fmaf(w, d1[0], acc2);
        acc3 = fmaf(w, d1[1], acc3);
    }

    // epilogue: all lanes active; half writes its node's 128B fp16 row slice
    float inv = 1.f / denom;         // denom >= 1 (self-loop term)
    int c = cl << 2;
    float4 bi = *(const float4*)(bias + c);
    float4 gg = *(const float4*)(g2 + c);
    float4 bb = *(const float4*)(b2 + c);
    float o0 = fmaxf(fmaf(acc0, inv, bi.x), 0.f) * gg.x + bb.x;
    float o1 = fmaxf(fmaf(acc1, inv, bi.y), 0.f) * gg.y + bb.y;
    float o2 = fmaxf(fmaf(acc2, inv, bi.z), 0.f) * gg.z + bb.z;
    float o3 = fmaxf(fmaf(acc3, inv, bi.w), 0.f) * gg.w + bb.w;
    ushort4 ov = {f2h(o0), f2h(o1), f2h(o2), f2h(o3)};
    *(ushort4*)(hout + (size_t)n * DH + c) = ov;
}

// ---- mean pool over sorted batch + final linear ---------------------------

__global__ __launch_bounds__(128) void k_pool1(const unsigned short* __restrict__ h,
                                               const int* __restrict__ batch,
                                               float* __restrict__ sums) {
    int c = threadIdx.x;
    int n0 = blockIdx.x * 64;
    int n1 = min(NN, n0 + 64);
    if (n0 >= NN) return;
    float acc = 0.f;
    int cur = batch[n0];
    for (int n = n0; n < n1; ++n) {
        int g = batch[n];
        if (g != cur) {
            atomicAdd(&sums[cur * DH + c], acc);
            acc = 0.f; cur = g;
        }
        acc += h2f(h[(size_t)n * DH + c]);
    }
    atomicAdd(&sums[cur * DH + c], acc);
}

__global__ __launch_bounds__(128) void k_pool2(const float* __restrict__ sums,
                                               const int* __restrict__ cnts,
                                               const float* __restrict__ lin_w,
                                               const float* __restrict__ lin_b,
                                               float* __restrict__ out) {
    __shared__ float sm[128];
    int g = blockIdx.x, c = threadIdx.x;
    float cnt = fmaxf((float)cnts[g], 1.f);
    sm[c] = (sums[g * DH + c] / cnt) * lin_w[c];
    __syncthreads();
    for (int off = 64; off >= 1; off >>= 1) {
        if (c < off) sm[c] += sm[c + off];
        __syncthreads();
    }
    if (c == 0) out[g] = sm[0] + lin_b[0];
}

// ---- launch ---------------------------------------------------------------

extern "C" void kernel_launch(void* const* d_in, const int* in_sizes, int n_in,
                              void* d_out, int out_size, void* d_ws, size_t ws_size,
                              hipStream_t stream) {
    const float* x     = (const float*)d_in[0];
    const int*   ei    = (const int*)d_in[1];
    const int*   batch = (const int*)d_in[2];
    const float* W     = (const float*)d_in[3];
    const float* a_src = (const float*)d_in[4];
    const float* a_dst = (const float*)d_in[5];
    const float* b     = (const float*)d_in[6];
    const float* bn_g  = (const float*)d_in[7];
    const float* bn_b  = (const float*)d_in[8];
    const float* bn_m  = (const float*)d_in[9];
    const float* bn_v  = (const float*)d_in[10];
    const float* lin_w = (const float*)d_in[11];
    const float* lin_b = (const float*)d_in[12];
    float* out = (float*)d_out;

    const int* srcp = ei;
    const int* dstp = ei + NE;

    char* wsp = (char*)d_ws;
    size_t off = 0;
    auto alloc = [&](size_t bytes) -> void* {
        void* p = wsp + off;
        off = (off + bytes + 511) & ~((size_t)511);
        return p;
    };
    unsigned char*  xq  = (unsigned char*)alloc((size_t)NN * DH);       // fp8 xp
    unsigned short* hb  = (unsigned short*)alloc((size_t)NN * DH * 2);  // fp16 h
    unsigned short* wtg = (unsigned short*)alloc((size_t)NL * DH * DH * 2);
    float* g2      = (float*)alloc((size_t)NL * DH * 4);
    float* b2      = (float*)alloc((size_t)NL * DH * 4);
    float* s_node  = (float*)alloc((size_t)NN * 4);
    float* d_node  = (float*)alloc((size_t)NN * 4);
    int*   row_ptr = (int*)alloc((size_t)(NN + 1) * 4);
    int*   csr_src = (int*)alloc((size_t)ET * 4);
    int*   pairs   = (int*)alloc((size_t)NBK * CAP * 4);
    int*   bcnt    = (int*)alloc((size_t)NBK * 4);
    float* sums    = (float*)alloc((size_t)NG * DH * 4);
    int*   cnts    = (int*)alloc((size_t)NG * 4);

    // zero accumulators up front
    hipError_t e0_ = hipMemsetAsync(bcnt, 0, (size_t)NBK * 4, stream); (void)e0_;
    hipError_t e1_ = hipMemsetAsync(sums, 0, (size_t)NG * DH * 4, stream); (void)e1_;
    hipError_t e2_ = hipMemsetAsync(cnts, 0, (size_t)NG * 4, stream); (void)e2_;

    // fused prep (wtg needed by k_mega's gemm half)
    k_prep<<<PW + PB + PC, 256, 0, stream>>>(W, wtg, bn_g, bn_b, bn_m, bn_v,
                                             g2, b2, batch, cnts);

    // layer-0 GEMM || CSR slab scatter, then finalize (self-scanned)
    k_mega<<<GB0 + SBK, 512, 0, stream>>>(x, wtg, a_src, a_dst, xq,
                                          s_node, d_node, srcp, dstp, bcnt, pairs);
    k_bfinal<<<NBK, 256, 0, stream>>>(pairs, bcnt, row_ptr, csr_src);

    for (int l = 0; l < NL; ++l) {
        if (l > 0)
            k_gemm<<<GB0, 512, 0, stream>>>(hb, wtg + (size_t)l * DH * DH,
                                            a_src + l * DH, a_dst + l * DH,
                                            xq, s_node, d_node);
        k_aggr<<<NN / 8, 256, 0, stream>>>(xq, s_node, d_node, row_ptr, csr_src,
                                           b + l * DH, g2 + l * DH, b2 + l * DH,
                                           hb);
    }

    k_pool1<<<(NN + 63) / 64, 128, 0, stream>>>(hb, batch, sums);
    k_pool2<<<NG, 128, 0, stream>>>(sums, cnts, lin_w, lin_b, out);
}

// Round 16
// 381.700 us; speedup vs baseline: 1.2302x; 1.2302x over previous
//
#include <hip/hip_runtime.h>
#include <hip/hip_fp16.h>
#include <math.h>

// simple_GAT: 5-layer GAT (heads=1) + BN(eval) + mean-pool + linear.
// R16: revert R15's unroll 16 -> 8 in k_aggr (16 cost +37% via occupancy/
// branch overhead). Keep: k_mega (layer-0 GEMM || CSR scatter), k_prep,
// GEMM fp8-out LDS bounce, self-scanning k_bfinal, slab CSR,
// 2-nodes/wave fp8 aggr (90MB FETCH = compulsory per-XCD floor).

#define NN 100000
#define NE 1600000
#define DH 128
#define NL 5
#define NG 64

static constexpr int ET = NE + NN;            // edges + self loops
static constexpr int NBK = (NN + 255) >> 8;   // 391 buckets of 256 dst nodes
static constexpr int CAP = 6144;              // slab capacity (mean 4348, sd 66)
static constexpr int GB0 = (NN + 127) / 128;  // 782 gemm blocks
static constexpr int SBK = (ET + 4095) / 4096;// 416 scatter blocks in k_mega
static constexpr int PW = (NL * DH * DH) / 256;        // 320
static constexpr int PB = (NL * DH + 255) / 256;       // 3
static constexpr int PC = (NN + 4095) / 4096;          // 25
static constexpr int LROW = 144;              // bounce-tile row stride (bytes)

typedef __attribute__((ext_vector_type(8))) _Float16 f16x8;
typedef __attribute__((ext_vector_type(4))) float f32x4;
typedef __attribute__((ext_vector_type(2))) float f32x2;

__device__ __forceinline__ unsigned short f2h(float v) {
    __half h = __float2half(v);
    return *reinterpret_cast<unsigned short*>(&h);
}
__device__ __forceinline__ float h2f(unsigned short u) {
    __half h = *reinterpret_cast<__half*>(&u);
    return __half2float(h);
}

// ---- fused prep: W transpose-cast | BN fold | graph counts ----------------

__global__ __launch_bounds__(256) void k_prep(const float* __restrict__ W,
                                              unsigned short* __restrict__ wtg,
                                              const float* __restrict__ ga,
                                              const float* __restrict__ be,
                                              const float* __restrict__ me,
                                              const float* __restrict__ va,
                                              float* __restrict__ g2,
                                              float* __restrict__ b2,
                                              const int* __restrict__ batch,
                                              int* __restrict__ cnts) {
    __shared__ int hc[NG];
    int bid = blockIdx.x, t = threadIdx.x;
    if (bid < PW) {
        int i = bid * 256 + t;
        int l = i >> 14, rem = i & 16383;
        int k = rem >> 7, c = rem & 127;
        wtg[(l << 14) + (c << 7) + k] = f2h(W[i]);   // wtg[l][c][k] = W[l][k][c]
    } else if (bid < PW + PB) {
        int i = (bid - PW) * 256 + t;
        if (i < NL * DH) {
            float s = ga[i] * rsqrtf(va[i] + 1e-5f);
            g2[i] = s;
            b2[i] = be[i] - me[i] * s;
        }
    } else {
        if (t < NG) hc[t] = 0;
        __syncthreads();
        int base = (bid - PW - PB) * 4096;
#pragma unroll
        for (int k = 0; k < 16; ++k) {
            int i = base + k * 256 + t;
            if (i < NN) atomicAdd(&hc[batch[i]], 1);
        }
        __syncthreads();
        if (t < NG && hc[t]) atomicAdd(&cnts[t], hc[t]);
    }
}

// ---- GEMM body (device): xp = h @ W + fused dots + fp8 out (LDS bounce) ---

template <bool F32IN>
__device__ __forceinline__ void gemm_body(char* lds, int bid,
                                          const void* __restrict__ Av,
                                          const unsigned short* __restrict__ Wt,
                                          const float* __restrict__ a_s,
                                          const float* __restrict__ a_d,
                                          unsigned char* __restrict__ xq,
                                          float* __restrict__ s_node,
                                          float* __restrict__ d_node) {
    int tid = threadIdx.x;
    int w = tid >> 6, l = tid & 63;
    int row0 = bid * 128;
    {   // stage Wt[col][k] fp16 with swizzle; 512 threads x 64B each
        int col = tid >> 2, seg = tid & 3;
        const char* srcp = (const char*)Wt + col * 256 + seg * 64;
#pragma unroll
        for (int i = 0; i < 4; ++i) {
            int off = seg * 64 + i * 16;
            *(uint4*)(lds + col * 256 + (off ^ ((col & 7) << 4))) =
                *(const uint4*)(srcp + i * 16);
        }
    }
    int arow = row0 + w * 16 + (l & 15);
    int arc = min(arow, NN - 1);
    f16x8 af[4];
    if constexpr (F32IN) {
        const float* ap = (const float*)Av + (size_t)arc * DH + ((l >> 4) << 3);
#pragma unroll
        for (int ks = 0; ks < 4; ++ks) {
            float4 u0 = *(const float4*)(ap + ks * 32);
            float4 u1 = *(const float4*)(ap + ks * 32 + 4);
            f16x8 v = {(_Float16)u0.x, (_Float16)u0.y, (_Float16)u0.z, (_Float16)u0.w,
                       (_Float16)u1.x, (_Float16)u1.y, (_Float16)u1.z, (_Float16)u1.w};
            af[ks] = v;
        }
    } else {
        const unsigned short* ap =
            (const unsigned short*)Av + (size_t)arc * DH + ((l >> 4) << 3);
#pragma unroll
        for (int ks = 0; ks < 4; ++ks)
            af[ks] = *(const f16x8*)(ap + ks * 32);
    }
    __syncthreads();

    f32x4 acc[8];
#pragma unroll
    for (int ct = 0; ct < 8; ++ct) acc[ct] = (f32x4){0.f, 0.f, 0.f, 0.f};
#pragma unroll
    for (int ct = 0; ct < 8; ++ct) {
        int col = ct * 16 + (l & 15);
        int cb = col * 256;
        int sw = (col & 7) << 4;
#pragma unroll
        for (int ks = 0; ks < 4; ++ks) {
            f16x8 bfr = *(const f16x8*)(lds + cb + ((ks * 64 + ((l >> 4) << 4)) ^ sw));
            acc[ct] = __builtin_amdgcn_mfma_f32_16x16x32_f16(af[ks], bfr, acc[ct], 0, 0, 0);
        }
    }

    float asv[8], adv[8];
#pragma unroll
    for (int ct = 0; ct < 8; ++ct) {
        asv[ct] = a_s[ct * 16 + (l & 15)];
        adv[ct] = a_d[ct * 16 + (l & 15)];
    }
    float ps[4] = {0.f, 0.f, 0.f, 0.f}, pd[4] = {0.f, 0.f, 0.f, 0.f};
#pragma unroll
    for (int ct = 0; ct < 8; ++ct)
#pragma unroll
        for (int r = 0; r < 4; ++r) {
            ps[r] = fmaf(acc[ct][r], asv[ct], ps[r]);
            pd[r] = fmaf(acc[ct][r], adv[ct], pd[r]);
        }
#pragma unroll
    for (int off = 8; off >= 1; off >>= 1)
#pragma unroll
        for (int r = 0; r < 4; ++r) {
            ps[r] += __shfl_xor(ps[r], off, 64);
            pd[r] += __shfl_xor(pd[r], off, 64);
        }
    int rbase = row0 + w * 16 + ((l >> 4) << 2);
    if ((l & 15) == 0) {
#pragma unroll
        for (int r = 0; r < 4; ++r) {
            int row = rbase + r;
            if (row < NN) { s_node[row] = ps[r]; d_node[row] = pd[r]; }
        }
    }

    // fp8 output via LDS bounce: byte-writes into stride-144 tile, then
    // coalesced uint4 stores (block tile = rows row0..row0+127 contiguous).
    __syncthreads();                 // W region reuse: all MFMA reads done
    int rl0 = w * 16 + ((l >> 4) << 2);
#pragma unroll
    for (int r = 0; r < 4; ++r) {
#pragma unroll
        for (int ct = 0; ct < 8; ++ct) {
            int pk = __builtin_amdgcn_cvt_pk_fp8_f32(acc[ct][r], 0.f, 0, false);
            lds[(rl0 + r) * LROW + ct * 16 + (l & 15)] = (char)(pk & 0xff);
        }
    }
    __syncthreads();
    size_t base = (size_t)row0 * DH;
    size_t limit = (size_t)NN * DH;
#pragma unroll
    for (int p = 0; p < 2; ++p) {
        int q = (tid + p * 512) * 16;             // byte pos in 16KB tile
        if (base + q < limit) {
            int row = q >> 7, col = q & 127;
            *(uint4*)(xq + base + q) = *(const uint4*)(lds + row * LROW + col);
        }
    }
}

// ---- CSR slab-scatter body (device) ---------------------------------------

__device__ __forceinline__ void bscatter_body(char* smem, int bid,
                                              const int* __restrict__ src,
                                              const int* __restrict__ dst,
                                              int* __restrict__ bcnt,
                                              int* __restrict__ pairs) {
    int* lcnt = (int*)smem;
    int* lbase = lcnt + NBK;
    for (int i = threadIdx.x; i < NBK; i += 512) lcnt[i] = 0;
    __syncthreads();
    int base = bid * 4096;
    int es[8], ed[8], er[8];
#pragma unroll
    for (int k = 0; k < 8; ++k) {
        int i = base + k * 512 + threadIdx.x;
        if (i < ET) {
            int s, d;
            if (i < NE) { s = src[i]; d = dst[i]; } else { s = d = i - NE; }
            es[k] = s; ed[k] = d;
            er[k] = atomicAdd(&lcnt[d >> 8], 1);
        } else {
            ed[k] = -1;
        }
    }
    __syncthreads();
    for (int i = threadIdx.x; i < NBK; i += 512)
        lbase[i] = lcnt[i] ? atomicAdd(&bcnt[i], lcnt[i]) : 0;
    __syncthreads();
#pragma unroll
    for (int k = 0; k < 8; ++k) {
        if (ed[k] >= 0) {
            int bk = ed[k] >> 8;
            pairs[(size_t)bk * CAP + lbase[bk] + er[k]] =
                es[k] | ((ed[k] & 255) << 17);
        }
    }
}

// ---- k_mega: layer-0 GEMM || CSR scatter (independent, one dispatch) ------

__global__ __launch_bounds__(512) void k_mega(const float* __restrict__ x,
                                              const unsigned short* __restrict__ Wt,
                                              const float* __restrict__ a_s,
                                              const float* __restrict__ a_d,
                                              unsigned char* __restrict__ xq,
                                              float* __restrict__ s_node,
                                              float* __restrict__ d_node,
                                              const int* __restrict__ src,
                                              const int* __restrict__ dst,
                                              int* __restrict__ bcnt,
                                              int* __restrict__ pairs) {
    __shared__ __align__(16) char smem[32768];
    if (blockIdx.x < GB0)
        gemm_body<true>(smem, blockIdx.x, x, Wt, a_s, a_d, xq, s_node, d_node);
    else
        bscatter_body(smem, blockIdx.x - GB0, src, dst, bcnt, pairs);
}

// ---- standalone GEMM for layers 1-4 ---------------------------------------

__global__ __launch_bounds__(512) void k_gemm(const unsigned short* __restrict__ A,
                                              const unsigned short* __restrict__ Wt,
                                              const float* __restrict__ a_s,
                                              const float* __restrict__ a_d,
                                              unsigned char* __restrict__ xq,
                                              float* __restrict__ s_node,
                                              float* __restrict__ d_node) {
    __shared__ __align__(16) char lds[32768];
    gemm_body<false>(lds, blockIdx.x, A, Wt, a_s, a_d, xq, s_node, d_node);
}

// ---- CSR finalize (self-computed prefix; k_bscan eliminated) --------------

__global__ __launch_bounds__(256) void k_bfinal(const int* __restrict__ pairs,
                                                const int* __restrict__ bcnt,
                                                int* __restrict__ row_ptr,
                                                int* __restrict__ csr_src) {
    __shared__ int ldeg[256];
    __shared__ int lcur[256];
    __shared__ int sm[256];
    int b = blockIdx.x, t = threadIdx.x;
    int n0 = b << 8;
    // compute e0 = sum(bcnt[0..b)) in-block (bcnt is 1.5KB, L2-hot)
    int psum = 0;
    for (int j = t; j < b; j += 256) psum += bcnt[j];
    sm[t] = psum;
    __syncthreads();
    for (int off = 128; off >= 1; off >>= 1) {
        if (t < off) sm[t] += sm[t + off];
        __syncthreads();
    }
    int e0 = sm[0];
    int cb = bcnt[b];
    __syncthreads();
    const int* slab = pairs + (size_t)b * CAP;
    ldeg[t] = 0;
    __syncthreads();
    for (int j = t; j < cb; j += 256)
        atomicAdd(&ldeg[(slab[j] >> 17) & 255], 1);
    __syncthreads();
    int v = ldeg[t];
    sm[t] = v;
    __syncthreads();
    for (int off = 1; off < 256; off <<= 1) {
        int u = (t >= off) ? sm[t - off] : 0;
        __syncthreads();
        sm[t] += u;
        __syncthreads();
    }
    int excl = sm[t] - v;
    lcur[t] = excl;
    int n = n0 + t;
    if (n < NN) row_ptr[n] = e0 + excl;
    if (b == 0 && t == 0) row_ptr[NN] = ET;
    __syncthreads();
    for (int j = t; j < cb; j += 256) {
        int p = slab[j];
        int local = atomicAdd(&lcur[(p >> 17) & 255], 1);
        csr_src[e0 + local] = p & 0x1FFFF;
    }
}

// ---- aggregation: 2 nodes per wave (half-wave per node); fp8 gather -------

__global__ __launch_bounds__(256) void k_aggr(const unsigned char* __restrict__ xq,
                                              const float* __restrict__ s_node,
                                              const float* __restrict__ d_node,
                                              const int* __restrict__ row_ptr,
                                              const int* __restrict__ csr_src,
                                              const float* __restrict__ bias,
                                              const float* __restrict__ g2,
                                              const float* __restrict__ b2,
                                              unsigned short* __restrict__ hout) {
    __shared__ float2 stash[4][2][64];
    int wid = threadIdx.x >> 6, lane = threadIdx.x & 63;
    int hi = lane >> 5, cl = lane & 31;
    int n = blockIdx.x * 8 + wid * 2 + hi;   // NN % 8 == 0 -> always valid
    int s0 = row_ptr[n], s1 = row_ptr[n + 1];
    int deg = s1 - s0;
    float dn = d_node[n];

    // prologue: slots cl and cl+32 of this node's edge list (deg<=64 typical)
    int off0 = 0, off1 = 0;
    float e0 = -1e30f, e1 = -1e30f;
    {
        int j0 = s0 + cl;
        if (j0 < s1) {
            int s = csr_src[j0];
            off0 = s << 7;                       // byte offset of fp8 row
            float t = s_node[s] + dn;
            e0 = (t >= 0.f) ? t : 0.2f * t;
        }
        int j1 = s0 + 32 + cl;
        if (j1 < s1) {
            int s = csr_src[j1];
            off1 = s << 7;
            float t = s_node[s] + dn;
            e1 = (t >= 0.f) ? t : 0.2f * t;
        }
    }
    float mx = fmaxf(e0, e1);
    for (int j = s0 + 64 + cl; j < s1; j += 32) {      // never in practice
        int s = csr_src[j];
        float t = s_node[s] + dn;
        t = (t >= 0.f) ? t : 0.2f * t;
        mx = fmaxf(mx, t);
    }
#pragma unroll
    for (int off = 16; off >= 1; off >>= 1)
        mx = fmaxf(mx, __shfl_xor(mx, off, 32));       // width-32: per-half

    float w0 = (e0 > -1e29f) ? __expf(e0 - mx) : 0.f;
    float w1 = (e1 > -1e29f) ? __expf(e1 - mx) : 0.f;
    float denom = w0 + w1;
#pragma unroll
    for (int off = 16; off >= 1; off >>= 1)
        denom += __shfl_xor(denom, off, 32);

    stash[wid][hi][cl]      = make_float2(w0, __int_as_float(off0));
    stash[wid][hi][cl + 32] = make_float2(w1, __int_as_float(off1));

    // gather: half-wave per edge; 4B fp8 per lane; HW pk decode; unroll 8
    unsigned int cl4 = (unsigned int)cl << 2;
    const char* xbase = (const char*)xq;
    float acc0 = 0.f, acc1 = 0.f, acc2 = 0.f, acc3 = 0.f;
    int cnt = min(deg, 64);
#pragma unroll 8
    for (int t = 0; t < cnt; ++t) {
        float2 p = stash[wid][hi][t];
        float w = p.x;
        unsigned int voff = (unsigned int)__float_as_int(p.y) + cl4;
        unsigned int v = *(const unsigned int*)(xbase + voff);
        f32x2 d0 = __builtin_amdgcn_cvt_pk_f32_fp8(v, false);
        f32x2 d1 = __builtin_amdgcn_cvt_pk_f32_fp8(v, true);
        acc0 = fmaf(w, d0[0], acc0);
        acc1 = fmaf(w, d0[1], acc1);
        acc2 = fmaf(w, d1[0], acc2);
        acc3 = fmaf(w, d1[1], acc3);
    }
    // tail fallback for deg>64 (statistically never; kept for correctness)
    for (int j = s0 + 64; j < s1; ++j) {
        int s = csr_src[j];
        float t = s_node[s] + dn;
        t = (t >= 0.f) ? t : 0.2f * t;
        float w = __expf(t - mx);
        denom += w;
        unsigned int voff = ((unsigned int)s << 7) + cl4;
        unsigned int v = *(const unsigned int*)(xbase + voff);
        f32x2 d0 = __builtin_amdgcn_cvt_pk_f32_fp8(v, false);
        f32x2 d1 = __builtin_amdgcn_cvt_pk_f32_fp8(v, true);
        acc0 = fmaf(w, d0[0], acc0);
        acc1 = fmaf(w, d0[1], acc1);
        acc2 = fmaf(w, d1[0], acc2);
        acc3 = fmaf(w, d1[1], acc3);
    }

    // epilogue: all lanes active; half writes its node's 128B fp16 row slice
    float inv = 1.f / denom;         // denom >= 1 (self-loop term)
    int c = cl << 2;
    float4 bi = *(const float4*)(bias + c);
    float4 gg = *(const float4*)(g2 + c);
    float4 bb = *(const float4*)(b2 + c);
    float o0 = fmaxf(fmaf(acc0, inv, bi.x), 0.f) * gg.x + bb.x;
    float o1 = fmaxf(fmaf(acc1, inv, bi.y), 0.f) * gg.y + bb.y;
    float o2 = fmaxf(fmaf(acc2, inv, bi.z), 0.f) * gg.z + bb.z;
    float o3 = fmaxf(fmaf(acc3, inv, bi.w), 0.f) * gg.w + bb.w;
    ushort4 ov = {f2h(o0), f2h(o1), f2h(o2), f2h(o3)};
    *(ushort4*)(hout + (size_t)n * DH + c) = ov;
}

// ---- mean pool over sorted batch + final linear ---------------------------

__global__ __launch_bounds__(128) void k_pool1(const unsigned short* __restrict__ h,
                                               const int* __restrict__ batch,
                                               float* __restrict__ sums) {
    int c = threadIdx.x;
    int n0 = blockIdx.x * 64;
    int n1 = min(NN, n0 + 64);
    if (n0 >= NN) return;
    float acc = 0.f;
    int cur = batch[n0];
    for (int n = n0; n < n1; ++n) {
        int g = batch[n];
        if (g != cur) {
            atomicAdd(&sums[cur * DH + c], acc);
            acc = 0.f; cur = g;
        }
        acc += h2f(h[(size_t)n * DH + c]);
    }
    atomicAdd(&sums[cur * DH + c], acc);
}

__global__ __launch_bounds__(128) void k_pool2(const float* __restrict__ sums,
                                               const int* __restrict__ cnts,
                                               const float* __restrict__ lin_w,
                                               const float* __restrict__ lin_b,
                                               float* __restrict__ out) {
    __shared__ float sm[128];
    int g = blockIdx.x, c = threadIdx.x;
    float cnt = fmaxf((float)cnts[g], 1.f);
    sm[c] = (sums[g * DH + c] / cnt) * lin_w[c];
    __syncthreads();
    for (int off = 64; off >= 1; off >>= 1) {
        if (c < off) sm[c] += sm[c + off];
        __syncthreads();
    }
    if (c == 0) out[g] = sm[0] + lin_b[0];
}

// ---- launch ---------------------------------------------------------------

extern "C" void kernel_launch(void* const* d_in, const int* in_sizes, int n_in,
                              void* d_out, int out_size, void* d_ws, size_t ws_size,
                              hipStream_t stream) {
    const float* x     = (const float*)d_in[0];
    const int*   ei    = (const int*)d_in[1];
    const int*   batch = (const int*)d_in[2];
    const float* W     = (const float*)d_in[3];
    const float* a_src = (const float*)d_in[4];
    const float* a_dst = (const float*)d_in[5];
    const float* b     = (const float*)d_in[6];
    const float* bn_g  = (const float*)d_in[7];
    const float* bn_b  = (const float*)d_in[8];
    const float* bn_m  = (const float*)d_in[9];
    const float* bn_v  = (const float*)d_in[10];
    const float* lin_w = (const float*)d_in[11];
    const float* lin_b = (const float*)d_in[12];
    float* out = (float*)d_out;

    const int* srcp = ei;
    const int* dstp = ei + NE;

    char* wsp = (char*)d_ws;
    size_t off = 0;
    auto alloc = [&](size_t bytes) -> void* {
        void* p = wsp + off;
        off = (off + bytes + 511) & ~((size_t)511);
        return p;
    };
    unsigned char*  xq  = (unsigned char*)alloc((size_t)NN * DH);       // fp8 xp
    unsigned short* hb  = (unsigned short*)alloc((size_t)NN * DH * 2);  // fp16 h
    unsigned short* wtg = (unsigned short*)alloc((size_t)NL * DH * DH * 2);
    float* g2      = (float*)alloc((size_t)NL * DH * 4);
    float* b2      = (float*)alloc((size_t)NL * DH * 4);
    float* s_node  = (float*)alloc((size_t)NN * 4);
    float* d_node  = (float*)alloc((size_t)NN * 4);
    int*   row_ptr = (int*)alloc((size_t)(NN + 1) * 4);
    int*   csr_src = (int*)alloc((size_t)ET * 4);
    int*   pairs   = (int*)alloc((size_t)NBK * CAP * 4);
    int*   bcnt    = (int*)alloc((size_t)NBK * 4);
    float* sums    = (float*)alloc((size_t)NG * DH * 4);
    int*   cnts    = (int*)alloc((size_t)NG * 4);

    // zero accumulators up front
    hipError_t e0_ = hipMemsetAsync(bcnt, 0, (size_t)NBK * 4, stream); (void)e0_;
    hipError_t e1_ = hipMemsetAsync(sums, 0, (size_t)NG * DH * 4, stream); (void)e1_;
    hipError_t e2_ = hipMemsetAsync(cnts, 0, (size_t)NG * 4, stream); (void)e2_;

    // fused prep (wtg needed by k_mega's gemm half)
    k_prep<<<PW + PB + PC, 256, 0, stream>>>(W, wtg, bn_g, bn_b, bn_m, bn_v,
                                             g2, b2, batch, cnts);

    // layer-0 GEMM || CSR slab scatter, then finalize (self-scanned)
    k_mega<<<GB0 + SBK, 512, 0, stream>>>(x, wtg, a_src, a_dst, xq,
                                          s_node, d_node, srcp, dstp, bcnt, pairs);
    k_bfinal<<<NBK, 256, 0, stream>>>(pairs, bcnt, row_ptr, csr_src);

    for (int l = 0; l < NL; ++l) {
        if (l > 0)
            k_gemm<<<GB0, 512, 0, stream>>>(hb, wtg + (size_t)l * DH * DH,
                                            a_src + l * DH, a_dst + l * DH,
                                            xq, s_node, d_node);
        k_aggr<<<NN / 8, 256, 0, stream>>>(xq, s_node, d_node, row_ptr, csr_src,
                                           b + l * DH, g2 + l * DH, b2 + l * DH,
                                           hb);
    }

    k_pool1<<<(NN + 63) / 64, 128, 0, stream>>>(hb, batch, sums);
    k_pool2<<<NG, 128, 0, stream>>>(sums, cnts, lin_w, lin_b, out);
}